// Round 5
// baseline (441.926 us; speedup 1.0000x reference)
//
#include <hip/hip_runtime.h>
#include <stdint.h>

#define S_LEN 2048
#define HIDDEN_ 2048
#define NH 16
#define QR 1536
#define KVR 512
#define DN 128
#define DR 64
#define DQK 192
#define DV 128

typedef __attribute__((ext_vector_type(8))) short bf16x8;
typedef __attribute__((ext_vector_type(4))) float f32x4;
typedef unsigned short u16;
typedef unsigned int u32;

#define GLOAD_LDS16(g, l)                                                      \
    __builtin_amdgcn_global_load_lds(                                          \
        (const __attribute__((address_space(1))) void*)(g),                    \
        (__attribute__((address_space(3))) void*)(l), 16, 0, 0)

__device__ inline float bf2f(u16 x) {
    union { u32 u; float f; } v; v.u = ((u32)x) << 16; return v.f;
}
__device__ inline u16 f2bf(float f) {
    union { float f; u32 u; } v; v.f = f;
    u32 u = v.u;
    return (u16)((u + 0x7fffu + ((u >> 16) & 1u)) >> 16);
}

// ---------------------------------------------------------------------------
// f32 -> bf16 conversion.
// ---------------------------------------------------------------------------
__global__ void cvt_f2b(const float* __restrict__ src, u16* __restrict__ dst, int n)
{
    int i = (blockIdx.x * 256 + threadIdx.x) * 4;
    if (i + 3 < n) {
        float4 v = *(const float4*)(src + i);
        dst[i + 0] = f2bf(v.x);
        dst[i + 1] = f2bf(v.y);
        dst[i + 2] = f2bf(v.z);
        dst[i + 3] = f2bf(v.w);
    }
}

// ---------------------------------------------------------------------------
// Generic bf16 GEMM: C[M,N] = A[M,K] @ B[N,K]^T, f32 accumulate.
// global_load_lds width-16 staging, 128x128 tile, BK=32.
// ---------------------------------------------------------------------------
__global__ __launch_bounds__(256, 2)
void gemm_bt(const u16* __restrict__ A, const u16* __restrict__ B,
             void* __restrict__ Cv, int M, int N, int K, int out_f32)
{
    __shared__ u16 sA[128 * 32];
    __shared__ u16 sB[128 * 32];
    const int tid  = threadIdx.x;
    const int wave = tid >> 6;
    const int lane = tid & 63;
    const int l16  = lane & 15;
    const int quad = lane >> 4;
    const int m_blk = blockIdx.y * 128;
    const int n_blk = blockIdx.x * 128;
    const int wm = (wave >> 1) * 64;
    const int wn = (wave & 1) * 64;

    const f32x4 zero4 = {0.f, 0.f, 0.f, 0.f};
    f32x4 acc[4][4];
#pragma unroll
    for (int i = 0; i < 4; i++)
#pragma unroll
        for (int j = 0; j < 4; j++) acc[i][j] = zero4;

    const int srow = lane >> 2;
    const int scol = (lane & 3) * 8;

    for (int k0 = 0; k0 < K; k0 += 32) {
        __syncthreads();
#pragma unroll
        for (int p = 0; p < 2; p++) {
            const int rbase = wave * 32 + p * 16;
            const int row = rbase + srow;
            const u16* ga = A + (size_t)(m_blk + row) * K + k0 + scol;
            GLOAD_LDS16(ga, &sA[rbase * 32]);
            int brow = n_blk + row; if (brow >= N) brow = N - 1;
            const u16* gb = B + (size_t)brow * K + k0 + scol;
            GLOAD_LDS16(gb, &sB[rbase * 32]);
        }
        __syncthreads();

        bf16x8 af[4], bfr[4];
#pragma unroll
        for (int i = 0; i < 4; i++)
            af[i] = *(const bf16x8*)(sA + (wm + i * 16 + l16) * 32 + quad * 8);
#pragma unroll
        for (int j = 0; j < 4; j++)
            bfr[j] = *(const bf16x8*)(sB + (wn + j * 16 + l16) * 32 + quad * 8);
#pragma unroll
        for (int i = 0; i < 4; i++)
#pragma unroll
            for (int j = 0; j < 4; j++)
                acc[i][j] = __builtin_amdgcn_mfma_f32_16x16x32_bf16(
                    af[i], bfr[j], acc[i][j], 0, 0, 0);
    }

#pragma unroll
    for (int i = 0; i < 4; i++)
#pragma unroll
        for (int j = 0; j < 4; j++)
#pragma unroll
            for (int r = 0; r < 4; r++) {
                int mrow = m_blk + wm + i * 16 + quad * 4 + r;
                int ncol = n_blk + wn + j * 16 + l16;
                if (ncol < N) {
                    if (out_f32)
                        ((float*)Cv)[(size_t)mrow * N + ncol] = acc[i][j][r];
                    else
                        ((u16*)Cv)[(size_t)mrow * N + ncol] = f2bf(acc[i][j][r]);
                }
            }
}

// ---------------------------------------------------------------------------
// RMSNorm over bf16 input rows; weight is the original f32 tensor.
// ---------------------------------------------------------------------------
__global__ void rmsnorm_k(const u16* __restrict__ X, const float* __restrict__ W,
                          u16* __restrict__ Y, int in_stride, int len, int out_stride)
{
    const int row = blockIdx.x;
    const u16* x = X + (size_t)row * in_stride;
    u16* y = Y + (size_t)row * out_stride;
    float ss = 0.f;
    for (int i = threadIdx.x; i < len; i += 256) { float v = bf2f(x[i]); ss += v * v; }
#pragma unroll
    for (int off = 32; off; off >>= 1) ss += __shfl_down(ss, off, 64);
    __shared__ float red[4];
    if ((threadIdx.x & 63) == 0) red[threadIdx.x >> 6] = ss;
    __syncthreads();
    float tot = red[0] + red[1] + red[2] + red[3];
    float inv = 1.0f / sqrtf(tot / (float)len + 1e-6f);
    for (int i = threadIdx.x; i < len; i += 256)
        y[i] = f2bf(W[i] * bf2f(x[i]) * inv);
}

// ---------------------------------------------------------------------------
// RoPE + repack Q/K into per-head contiguous layouts:
//   Q [H][S][192], K [H][S][192]
// ---------------------------------------------------------------------------
__global__ void rope_repack(const u16* __restrict__ q,      // [S][H*192]
                            const u16* __restrict__ kvb,    // [S][H*256]
                            const u16* __restrict__ kva_pe, // [S][*] stride kva_stride
                            int kva_stride,
                            u16* __restrict__ Q, u16* __restrict__ Kf)
{
    const int s = blockIdx.x;
    const float pos = (float)s;
    const int t = threadIdx.x;
    __shared__ float cs[64], sn[64];
    __shared__ u16 kpe_r[64];
    if (t < 64) {
        int jf = t & 31;
        float freq = powf(10000.f, -(float)(2 * jf) / 64.f);
        float ang = pos * freq;
        cs[t] = cosf(ang);
        sn[t] = sinf(ang);
    }
    __syncthreads();
    if (t < 64) {
        int j = t;
        float x = bf2f(kva_pe[(size_t)s * kva_stride + j]);
        float other = (j < 32) ? -bf2f(kva_pe[(size_t)s * kva_stride + j + 32])
                               :  bf2f(kva_pe[(size_t)s * kva_stride + j - 32]);
        kpe_r[j] = f2bf(x * cs[j] + other * sn[j]);
    }
    __syncthreads();

    for (int idx = t; idx < NH * DQK; idx += 256) {
        int h = idx / DQK, d = idx % DQK;
        const size_t qrow = (size_t)s * (NH * DQK) + h * DQK;
        u16 qv;
        if (d < DN) qv = q[qrow + d];
        else {
            int j = d - DN;
            float x = bf2f(q[qrow + DN + j]);
            float other = (j < 32) ? -bf2f(q[qrow + DN + j + 32])
                                   :  bf2f(q[qrow + DN + j - 32]);
            qv = f2bf(x * cs[j] + other * sn[j]);
        }
        Q[((size_t)h * S_LEN + s) * DQK + d] = qv;
        u16 kv;
        if (d < DN) kv = kvb[(size_t)s * (NH * 256) + h * 256 + d];
        else        kv = kpe_r[d - DN];
        Kf[((size_t)h * S_LEN + s) * DQK + d] = kv;
    }
}

// ---------------------------------------------------------------------------
// V transpose straight out of kvb: Vt[h][d][s] = kvb[s][h*256+128+d].
// ---------------------------------------------------------------------------
__global__ void transpose_v(const u16* __restrict__ kvb, u16* __restrict__ Vt)
{
    __shared__ u16 tile[64][72];
    const int h  = blockIdx.z;
    const int s0 = blockIdx.x * 64;
    const int d0 = blockIdx.y * 64;
    const int t  = threadIdx.x;
#pragma unroll
    for (int p = 0; p < 2; p++) {
        int c = p * 256 + t;
        int r = c >> 3, col = (c & 7) * 8;
        *(bf16x8*)&tile[r][col] =
            *(const bf16x8*)&kvb[(size_t)(s0 + r) * (NH * 256) + h * 256 + 128 + d0 + col];
    }
    __syncthreads();
#pragma unroll
    for (int p = 0; p < 2; p++) {
        int c = p * 256 + t;
        int dr = c >> 3, sc = (c & 7) * 8;
        bf16x8 v;
#pragma unroll
        for (int j = 0; j < 8; j++) v[j] = (short)tile[sc + j][dr];
        *(bf16x8*)&Vt[((size_t)h * DV + d0 + dr) * S_LEN + s0 + sc] = v;
    }
}

// ---------------------------------------------------------------------------
// Causal flash attention, block-shared K/V staging, DOUBLE-BUFFERED:
// per k-step: barrier -> issue async prefetch of tile kt+1 into buf^1 ->
// compute tile kt from buf. The compiler's vmcnt(0) drain at the next
// barrier lands after compute has overlapped the prefetch latency.
// Grid (32, NH); heads 0-7 strip=bx, heads 8-15 strip=31-bx (CU pairing).
// LDS chunk-transposed layout (chunk = cg*ROWS+row) satisfies the
// global_load_lds lane-contiguity rule and is conflict-free on ds_read_b128.
// ---------------------------------------------------------------------------
__global__ __launch_bounds__(256, 2)
void mla_attn(const u16* __restrict__ Q, const u16* __restrict__ Kf,
              const u16* __restrict__ Vt, u16* __restrict__ attn)
{
    const int h     = blockIdx.y;
    const int strip = (h < 8) ? blockIdx.x : (31 - blockIdx.x);
    const int wave  = threadIdx.x >> 6;
    const int lane  = threadIdx.x & 63;
    const int l16   = lane & 15;
    const int quad  = lane >> 4;
    const int q0    = strip * 64 + wave * 16;

    const u16* Qh  = Q  + (size_t)h * S_LEN * DQK;
    const u16* Kh  = Kf + (size_t)h * S_LEN * DQK;
    const u16* Vth = Vt + (size_t)h * DV * S_LEN;

    __shared__ u16 sK[2][24 * 32 * 8];    // 2 x 12 KB
    __shared__ u16 sV[2][4 * 128 * 8];    // 2 x  8 KB
    __shared__ u16 pbuf[4][16][36];       // 4.5 KB
    u16 (*pb)[36] = pbuf[wave];

    bf16x8 qf[6];
#pragma unroll
    for (int st = 0; st < 6; st++)
        qf[st] = *(const bf16x8*)(Qh + (size_t)(q0 + l16) * DQK + st * 32 + quad * 8);

    const f32x4 zero4 = {0.f, 0.f, 0.f, 0.f};
    f32x4 oacc[8];
#pragma unroll
    for (int t = 0; t < 8; t++) oacc[t] = zero4;
    float mrow[4], lrow[4];
#pragma unroll
    for (int r = 0; r < 4; r++) { mrow[r] = -INFINITY; lrow[r] = 0.f; }

    const float scale = 0.07216878364870323f;  // 192^-0.5
    const int T = 2 * strip + 2;               // block-uniform tile count

    auto stage = [&](int buf, int c0) {
#pragma unroll
        for (int g = 0; g < 3; g++) {
            int c = g * 256 + wave * 64 + lane;
            int row = c & 31, cg = c >> 5;
            GLOAD_LDS16(Kh + (size_t)(c0 + row) * DQK + cg * 8,
                        &sK[buf][(g * 256 + wave * 64) * 8]);
        }
#pragma unroll
        for (int g = 0; g < 2; g++) {
            int c = g * 256 + wave * 64 + lane;
            int d = c & 127, cg = c >> 7;
            GLOAD_LDS16(Vth + (size_t)d * S_LEN + c0 + cg * 8,
                        &sV[buf][(g * 256 + wave * 64) * 8]);
        }
    };

    stage(0, 0);   // prologue: tile 0 into buffer 0

    for (int kt = 0; kt < T; kt++) {
        const int c0  = kt * 32;
        const int cur = kt & 1;
        __syncthreads();   // drains prefetch of buf[cur]; frees buf[cur^1]
        if (kt + 1 < T) stage(cur ^ 1, c0 + 32);   // async prefetch next tile

        if (c0 <= q0 + 15) {   // wave causally active for this tile
            f32x4 s0 = zero4, s1 = zero4;
#pragma unroll
            for (int st = 0; st < 6; st++) {
                bf16x8 k0 = *(const bf16x8*)&sK[cur][((st * 4 + quad) * 32 + l16) * 8];
                bf16x8 k1 = *(const bf16x8*)&sK[cur][((st * 4 + quad) * 32 + 16 + l16) * 8];
                s0 = __builtin_amdgcn_mfma_f32_16x16x32_bf16(qf[st], k0, s0, 0, 0, 0);
                s1 = __builtin_amdgcn_mfma_f32_16x16x32_bf16(qf[st], k1, s1, 0, 0, 0);
            }
            bf16x8 vfr[8];
#pragma unroll
            for (int t = 0; t < 8; t++)
                vfr[t] = *(const bf16x8*)&sV[cur][(quad * 128 + t * 16 + l16) * 8];

            const bool full = (c0 + 31 <= q0);
#pragma unroll
            for (int r = 0; r < 4; r++) {
                const int row = q0 + quad * 4 + r;
                float v0 = s0[r] * scale, v1 = s1[r] * scale;
                if (!full) {
                    if (c0 + l16 > row)      v0 = -INFINITY;
                    if (c0 + 16 + l16 > row) v1 = -INFINITY;
                }
                float lm = fmaxf(v0, v1);
#pragma unroll
                for (int off = 1; off < 16; off <<= 1)
                    lm = fmaxf(lm, __shfl_xor(lm, off, 16));
                float mnew  = fmaxf(mrow[r], lm);
                float alpha = __expf(mrow[r] - mnew);
                float p0 = __expf(v0 - mnew), p1 = __expf(v1 - mnew);
                float rs = p0 + p1;
#pragma unroll
                for (int off = 1; off < 16; off <<= 1)
                    rs += __shfl_xor(rs, off, 16);
                lrow[r] = lrow[r] * alpha + rs;
                mrow[r] = mnew;
#pragma unroll
                for (int t = 0; t < 8; t++) oacc[t][r] *= alpha;
                pb[quad * 4 + r][l16]      = f2bf(p0);
                pb[quad * 4 + r][16 + l16] = f2bf(p1);
            }
            asm volatile("s_waitcnt lgkmcnt(0)" ::: "memory");
            bf16x8 pfrag = *(const bf16x8*)(&pb[l16][quad * 8]);

#pragma unroll
            for (int t = 0; t < 8; t++)
                oacc[t] = __builtin_amdgcn_mfma_f32_16x16x32_bf16(pfrag, vfr[t],
                                                                  oacc[t], 0, 0, 0);
        }
    }

#pragma unroll
    for (int t = 0; t < 8; t++)
#pragma unroll
        for (int r = 0; r < 4; r++) {
            int row = q0 + quad * 4 + r;
            float o = oacc[t][r] / lrow[r];
            attn[(size_t)row * (NH * DV) + h * DV + t * 16 + l16] = f2bf(o);
        }
}

// ---------------------------------------------------------------------------
extern "C" void kernel_launch(void* const* d_in, const int* in_sizes, int n_in,
                              void* d_out, int out_size, void* d_ws, size_t ws_size,
                              hipStream_t stream)
{
    const float* hid      = (const float*)d_in[0];
    // d_in[1] = position_ids (== arange(s)); sequence index used directly.
    const float* q_a_w    = (const float*)d_in[2];
    const float* q_a_ln_w = (const float*)d_in[3];
    const float* q_b_w    = (const float*)d_in[4];
    const float* kv_a_w   = (const float*)d_in[5];
    const float* kv_a_ln_w= (const float*)d_in[6];
    const float* kv_b_w   = (const float*)d_in[7];
    const float* o_w      = (const float*)d_in[8];

    const int NQKV = QR + KVR + DR;   // 2112: merged q_a_w ++ kv_a_w rows

    char* base = (char*)d_ws;
    u16* qkvaw_b = (u16*)(base + 0);          //  8,650,752  [2112,2048]
    u16* qbw_b   = (u16*)(base + 8650752);    //  9,437,184  [3072,1536]
    u16* kvbw_b  = (u16*)(base + 18087936);   //  4,194,304  [4096,512]
    u16* ow_b    = (u16*)(base + 22282240);   //  8,388,608  [2048,2048]
    u16* hid_b   = (u16*)(base + 30670848);   //  8,388,608  [2048,2048]
    u16* qkv_a   = (u16*)(base + 39059456);   //  8,650,752  [2048,2112]
    u16* q_n     = (u16*)(base + 47710208);   //  6,291,456  [2048,1536]
    u16* ckv     = (u16*)(base + 54001664);   //  2,097,152  [2048,512]
    u16* qb      = (u16*)(base + 56098816);   // 12,582,912  [2048,3072]
    u16* kvb     = (u16*)(base + 68681728);   // 16,777,216  [2048,4096]
    u16* Qb      = (u16*)(base + 85458944);   // 12,582,912  [16][2048][192]
    u16* Kb      = (u16*)(base + 98041856);   // 12,582,912
    u16* Vtb     = (u16*)(base + 110624768);  //  8,388,608  [16][128][2048]
    u16* attnb   = (u16*)(base + 39059456);   // reuse qkv_a (dead after rope)

    // 0) convert f32 inputs/weights to bf16
    cvt_f2b<<<HIDDEN_ * S_LEN / 1024, 256, 0, stream>>>(hid, hid_b, HIDDEN_ * S_LEN);
    cvt_f2b<<<QR * HIDDEN_ / 1024, 256, 0, stream>>>(q_a_w, qkvaw_b, QR * HIDDEN_);
    cvt_f2b<<<(KVR + DR) * HIDDEN_ / 1024, 256, 0, stream>>>(
        kv_a_w, qkvaw_b + (size_t)QR * HIDDEN_, (KVR + DR) * HIDDEN_);
    cvt_f2b<<<NH * DQK * QR / 1024, 256, 0, stream>>>(q_b_w, qbw_b, NH * DQK * QR);
    cvt_f2b<<<NH * 256 * KVR / 1024, 256, 0, stream>>>(kv_b_w, kvbw_b, NH * 256 * KVR);
    cvt_f2b<<<HIDDEN_ * NH * DV / 1024, 256, 0, stream>>>(o_w, ow_b, HIDDEN_ * NH * DV);

    // 1) qkv_a = hidden @ [q_a_w; kv_a_w]^T   [2048,2112]
    gemm_bt<<<dim3((NQKV + 127) / 128, S_LEN / 128), 256, 0, stream>>>(
        hid_b, qkvaw_b, qkv_a, S_LEN, NQKV, HIDDEN_, 0);
    // 2) q_n = rmsnorm(qkv_a[:, :1536])
    rmsnorm_k<<<S_LEN, 256, 0, stream>>>(qkv_a, q_a_ln_w, q_n, NQKV, QR, QR);
    // 3) ckv = rmsnorm(qkv_a[:, 1536:2048])
    rmsnorm_k<<<S_LEN, 256, 0, stream>>>(qkv_a + QR, kv_a_ln_w, ckv, NQKV, KVR, KVR);
    // 4) qb = q_n @ q_b_w^T           [2048,3072]
    gemm_bt<<<dim3(NH * DQK / 128, S_LEN / 128), 256, 0, stream>>>(
        q_n, qbw_b, qb, S_LEN, NH * DQK, QR, 0);
    // 5) kvb = ckv @ kv_b_w^T         [2048,4096]
    gemm_bt<<<dim3(NH * 256 / 128, S_LEN / 128), 256, 0, stream>>>(
        ckv, kvbw_b, kvb, S_LEN, NH * 256, KVR, 0);
    // 6) rope + repack Q/K (k_pe = qkv_a cols 2048..2111)
    rope_repack<<<S_LEN, 256, 0, stream>>>(qb, kvb, qkv_a + QR + KVR, NQKV, Qb, Kb);
    // 6b) V transpose: Vt[h][d][s]
    transpose_v<<<dim3(S_LEN / 64, DV / 64, NH), 256, 0, stream>>>(kvb, Vtb);
    // 7) causal flash attention -> attnb [2048, 2048]
    mla_attn<<<dim3(32, NH), 256, 0, stream>>>(Qb, Kb, Vtb, attnb);
    // 8) out = attnb @ o_w^T          [2048,2048], f32 output
    gemm_bt<<<dim3(HIDDEN_ / 128, S_LEN / 128), 256, 0, stream>>>(
        attnb, ow_b, (float*)d_out, S_LEN, HIDDEN_, HIDDEN_, 1);
}

// Round 6
// 414.667 us; speedup vs baseline: 1.0657x; 1.0657x over previous
//
#include <hip/hip_runtime.h>
#include <stdint.h>

#define S_LEN 2048
#define HIDDEN_ 2048
#define NH 16
#define QR 1536
#define KVR 512
#define DN 128
#define DR 64
#define DQK 192
#define DV 128

typedef __attribute__((ext_vector_type(8))) short bf16x8;
typedef __attribute__((ext_vector_type(4))) float f32x4;
typedef __attribute__((ext_vector_type(4))) unsigned short u16x4;
typedef unsigned short u16;
typedef unsigned int u32;

#define GLOAD_LDS16(g, l)                                                      \
    __builtin_amdgcn_global_load_lds(                                          \
        (const __attribute__((address_space(1))) void*)(g),                    \
        (__attribute__((address_space(3))) void*)(l), 16, 0, 0)

__device__ inline float bf2f(u16 x) {
    union { u32 u; float f; } v; v.u = ((u32)x) << 16; return v.f;
}
__device__ inline u16 f2bf(float f) {
    union { float f; u32 u; } v; v.f = f;
    u32 u = v.u;
    return (u16)((u + 0x7fffu + ((u >> 16) & 1u)) >> 16);
}

// ---------------------------------------------------------------------------
// f32 -> bf16 conversion.
// ---------------------------------------------------------------------------
__global__ void cvt_f2b(const float* __restrict__ src, u16* __restrict__ dst, int n)
{
    int i = (blockIdx.x * 256 + threadIdx.x) * 4;
    if (i + 3 < n) {
        float4 v = *(const float4*)(src + i);
        dst[i + 0] = f2bf(v.x);
        dst[i + 1] = f2bf(v.y);
        dst[i + 2] = f2bf(v.z);
        dst[i + 3] = f2bf(v.w);
    }
}

// ---------------------------------------------------------------------------
// Generic bf16 GEMM: C[M,N] = A[M,K] @ B[N,K]^T, f32 accumulate.
// global_load_lds width-16 staging, 128x128 tile, BK=32.
// ---------------------------------------------------------------------------
__global__ __launch_bounds__(256, 2)
void gemm_bt(const u16* __restrict__ A, const u16* __restrict__ B,
             void* __restrict__ Cv, int M, int N, int K, int out_f32)
{
    __shared__ u16 sA[128 * 32];
    __shared__ u16 sB[128 * 32];
    const int tid  = threadIdx.x;
    const int wave = tid >> 6;
    const int lane = tid & 63;
    const int l16  = lane & 15;
    const int quad = lane >> 4;
    const int m_blk = blockIdx.y * 128;
    const int n_blk = blockIdx.x * 128;
    const int wm = (wave >> 1) * 64;
    const int wn = (wave & 1) * 64;

    const f32x4 zero4 = {0.f, 0.f, 0.f, 0.f};
    f32x4 acc[4][4];
#pragma unroll
    for (int i = 0; i < 4; i++)
#pragma unroll
        for (int j = 0; j < 4; j++) acc[i][j] = zero4;

    const int srow = lane >> 2;
    const int scol = (lane & 3) * 8;

    for (int k0 = 0; k0 < K; k0 += 32) {
        __syncthreads();
#pragma unroll
        for (int p = 0; p < 2; p++) {
            const int rbase = wave * 32 + p * 16;
            const int row = rbase + srow;
            const u16* ga = A + (size_t)(m_blk + row) * K + k0 + scol;
            GLOAD_LDS16(ga, &sA[rbase * 32]);
            int brow = n_blk + row; if (brow >= N) brow = N - 1;
            const u16* gb = B + (size_t)brow * K + k0 + scol;
            GLOAD_LDS16(gb, &sB[rbase * 32]);
        }
        __syncthreads();

        bf16x8 af[4], bfr[4];
#pragma unroll
        for (int i = 0; i < 4; i++)
            af[i] = *(const bf16x8*)(sA + (wm + i * 16 + l16) * 32 + quad * 8);
#pragma unroll
        for (int j = 0; j < 4; j++)
            bfr[j] = *(const bf16x8*)(sB + (wn + j * 16 + l16) * 32 + quad * 8);
#pragma unroll
        for (int i = 0; i < 4; i++)
#pragma unroll
            for (int j = 0; j < 4; j++)
                acc[i][j] = __builtin_amdgcn_mfma_f32_16x16x32_bf16(
                    af[i], bfr[j], acc[i][j], 0, 0, 0);
    }

#pragma unroll
    for (int i = 0; i < 4; i++)
#pragma unroll
        for (int j = 0; j < 4; j++)
#pragma unroll
            for (int r = 0; r < 4; r++) {
                int mrow = m_blk + wm + i * 16 + quad * 4 + r;
                int ncol = n_blk + wn + j * 16 + l16;
                if (ncol < N) {
                    if (out_f32)
                        ((float*)Cv)[(size_t)mrow * N + ncol] = acc[i][j][r];
                    else
                        ((u16*)Cv)[(size_t)mrow * N + ncol] = f2bf(acc[i][j][r]);
                }
            }
}

// ---------------------------------------------------------------------------
// RMSNorm over bf16 input rows; weight is the original f32 tensor.
// ---------------------------------------------------------------------------
__global__ void rmsnorm_k(const u16* __restrict__ X, const float* __restrict__ W,
                          u16* __restrict__ Y, int in_stride, int len, int out_stride)
{
    const int row = blockIdx.x;
    const u16* x = X + (size_t)row * in_stride;
    u16* y = Y + (size_t)row * out_stride;
    float ss = 0.f;
    for (int i = threadIdx.x; i < len; i += 256) { float v = bf2f(x[i]); ss += v * v; }
#pragma unroll
    for (int off = 32; off; off >>= 1) ss += __shfl_down(ss, off, 64);
    __shared__ float red[4];
    if ((threadIdx.x & 63) == 0) red[threadIdx.x >> 6] = ss;
    __syncthreads();
    float tot = red[0] + red[1] + red[2] + red[3];
    float inv = 1.0f / sqrtf(tot / (float)len + 1e-6f);
    for (int i = threadIdx.x; i < len; i += 256)
        y[i] = f2bf(W[i] * bf2f(x[i]) * inv);
}

// ---------------------------------------------------------------------------
// RoPE + repack Q/K into per-head contiguous layouts:
//   Q [H][S][192], K [H][S][192]
// ---------------------------------------------------------------------------
__global__ void rope_repack(const u16* __restrict__ q,      // [S][H*192]
                            const u16* __restrict__ kvb,    // [S][H*256]
                            const u16* __restrict__ kva_pe, // [S][*] stride kva_stride
                            int kva_stride,
                            u16* __restrict__ Q, u16* __restrict__ Kf)
{
    const int s = blockIdx.x;
    const float pos = (float)s;
    const int t = threadIdx.x;
    __shared__ float cs[64], sn[64];
    __shared__ u16 kpe_r[64];
    if (t < 64) {
        int jf = t & 31;
        float freq = powf(10000.f, -(float)(2 * jf) / 64.f);
        float ang = pos * freq;
        cs[t] = cosf(ang);
        sn[t] = sinf(ang);
    }
    __syncthreads();
    if (t < 64) {
        int j = t;
        float x = bf2f(kva_pe[(size_t)s * kva_stride + j]);
        float other = (j < 32) ? -bf2f(kva_pe[(size_t)s * kva_stride + j + 32])
                               :  bf2f(kva_pe[(size_t)s * kva_stride + j - 32]);
        kpe_r[j] = f2bf(x * cs[j] + other * sn[j]);
    }
    __syncthreads();

    for (int idx = t; idx < NH * DQK; idx += 256) {
        int h = idx / DQK, d = idx % DQK;
        const size_t qrow = (size_t)s * (NH * DQK) + h * DQK;
        u16 qv;
        if (d < DN) qv = q[qrow + d];
        else {
            int j = d - DN;
            float x = bf2f(q[qrow + DN + j]);
            float other = (j < 32) ? -bf2f(q[qrow + DN + j + 32])
                                   :  bf2f(q[qrow + DN + j - 32]);
            qv = f2bf(x * cs[j] + other * sn[j]);
        }
        Q[((size_t)h * S_LEN + s) * DQK + d] = qv;
        u16 kv;
        if (d < DN) kv = kvb[(size_t)s * (NH * 256) + h * 256 + d];
        else        kv = kpe_r[d - DN];
        Kf[((size_t)h * S_LEN + s) * DQK + d] = kv;
    }
}

// ---------------------------------------------------------------------------
// V transpose straight out of kvb: Vt[h][d][s] = kvb[s][h*256+128+d].
// ---------------------------------------------------------------------------
__global__ void transpose_v(const u16* __restrict__ kvb, u16* __restrict__ Vt)
{
    __shared__ u16 tile[64][72];
    const int h  = blockIdx.z;
    const int s0 = blockIdx.x * 64;
    const int d0 = blockIdx.y * 64;
    const int t  = threadIdx.x;
#pragma unroll
    for (int p = 0; p < 2; p++) {
        int c = p * 256 + t;
        int r = c >> 3, col = (c & 7) * 8;
        *(bf16x8*)&tile[r][col] =
            *(const bf16x8*)&kvb[(size_t)(s0 + r) * (NH * 256) + h * 256 + 128 + d0 + col];
    }
    __syncthreads();
#pragma unroll
    for (int p = 0; p < 2; p++) {
        int c = p * 256 + t;
        int dr = c >> 3, sc = (c & 7) * 8;
        bf16x8 v;
#pragma unroll
        for (int j = 0; j < 8; j++) v[j] = (short)tile[sc + j][dr];
        *(bf16x8*)&Vt[((size_t)h * DV + d0 + dr) * S_LEN + s0 + sc] = v;
    }
}

// ---------------------------------------------------------------------------
// Causal flash attention, S^T-layout softmax.
// QK^T computed TRANSPOSED (A=K, B=Q) so lane's l16 = q-row, quads/regs = k.
// Row softmax: local max/sum over 8 regs + 2 shfl_xor (vs 32 shuffles before).
// m/l/alpha are one scalar per lane. PV: A=V^T-frag, B=P-frag -> out^T in
// regs, alpha/l already lane-aligned. All LDS reads identical to the
// previously-verified kernel; only MFMA operand order + reductions change.
// Double-buffered K/V staging via global_load_lds (chunk-transposed layout).
// ---------------------------------------------------------------------------
__global__ __launch_bounds__(256, 2)
void mla_attn(const u16* __restrict__ Q, const u16* __restrict__ Kf,
              const u16* __restrict__ Vt, u16* __restrict__ attn)
{
    const int h     = blockIdx.y;
    const int strip = (h < 8) ? blockIdx.x : (31 - blockIdx.x);
    const int wave  = threadIdx.x >> 6;
    const int lane  = threadIdx.x & 63;
    const int l16   = lane & 15;
    const int quad  = lane >> 4;
    const int q0    = strip * 64 + wave * 16;
    const int qrow  = q0 + l16;          // this lane's q row

    const u16* Qh  = Q  + (size_t)h * S_LEN * DQK;
    const u16* Kh  = Kf + (size_t)h * S_LEN * DQK;
    const u16* Vth = Vt + (size_t)h * DV * S_LEN;

    __shared__ u16 sK[2][24 * 32 * 8];    // 2 x 12 KB
    __shared__ u16 sV[2][4 * 128 * 8];    // 2 x  8 KB
    __shared__ u16 pbuf[4][16][36];       // 4.5 KB
    u16 (*pb)[36] = pbuf[wave];

    bf16x8 qf[6];
#pragma unroll
    for (int st = 0; st < 6; st++)
        qf[st] = *(const bf16x8*)(Qh + (size_t)qrow * DQK + st * 32 + quad * 8);

    const f32x4 zero4 = {0.f, 0.f, 0.f, 0.f};
    f32x4 oacc[8];
#pragma unroll
    for (int t = 0; t < 8; t++) oacc[t] = zero4;
    float mrow = -INFINITY, lrow = 0.f;

    const float scale = 0.07216878364870323f;  // 192^-0.5
    const int T = 2 * strip + 2;               // block-uniform tile count

    auto stage = [&](int buf, int c0) {
#pragma unroll
        for (int g = 0; g < 3; g++) {
            int c = g * 256 + wave * 64 + lane;
            int row = c & 31, cg = c >> 5;
            GLOAD_LDS16(Kh + (size_t)(c0 + row) * DQK + cg * 8,
                        &sK[buf][(g * 256 + wave * 64) * 8]);
        }
#pragma unroll
        for (int g = 0; g < 2; g++) {
            int c = g * 256 + wave * 64 + lane;
            int d = c & 127, cg = c >> 7;
            GLOAD_LDS16(Vth + (size_t)d * S_LEN + c0 + cg * 8,
                        &sV[buf][(g * 256 + wave * 64) * 8]);
        }
    };

    stage(0, 0);   // prologue: tile 0 into buffer 0

    for (int kt = 0; kt < T; kt++) {
        const int c0  = kt * 32;
        const int cur = kt & 1;
        __syncthreads();
        if (kt + 1 < T) stage(cur ^ 1, c0 + 32);

        if (c0 <= q0 + 15) {
            // S^T: s0/s1 reg r, lane(quad,l16) = S^T[k=c0+(16?)+quad*4+r][q=qrow]
            f32x4 s0 = zero4, s1 = zero4;
#pragma unroll
            for (int st = 0; st < 6; st++) {
                bf16x8 k0 = *(const bf16x8*)&sK[cur][((st * 4 + quad) * 32 + l16) * 8];
                bf16x8 k1 = *(const bf16x8*)&sK[cur][((st * 4 + quad) * 32 + 16 + l16) * 8];
                s0 = __builtin_amdgcn_mfma_f32_16x16x32_bf16(k0, qf[st], s0, 0, 0, 0);
                s1 = __builtin_amdgcn_mfma_f32_16x16x32_bf16(k1, qf[st], s1, 0, 0, 0);
            }
            bf16x8 vfr[8];
#pragma unroll
            for (int t = 0; t < 8; t++)
                vfr[t] = *(const bf16x8*)&sV[cur][(quad * 128 + t * 16 + l16) * 8];

            const bool full = (c0 + 31 <= q0);
            float v0[4], v1[4];
#pragma unroll
            for (int r = 0; r < 4; r++) {
                v0[r] = s0[r] * scale;
                v1[r] = s1[r] * scale;
                if (!full) {
                    if (c0 + quad * 4 + r > qrow)      v0[r] = -INFINITY;
                    if (c0 + 16 + quad * 4 + r > qrow) v1[r] = -INFINITY;
                }
            }
            float lm = fmaxf(fmaxf(fmaxf(v0[0], v0[1]), fmaxf(v0[2], v0[3])),
                             fmaxf(fmaxf(v1[0], v1[1]), fmaxf(v1[2], v1[3])));
            lm = fmaxf(lm, __shfl_xor(lm, 16, 64));
            lm = fmaxf(lm, __shfl_xor(lm, 32, 64));
            const float mnew  = fmaxf(mrow, lm);
            const float alpha = __expf(mrow - mnew);
            float p0[4], p1[4], rs = 0.f;
#pragma unroll
            for (int r = 0; r < 4; r++) {
                p0[r] = __expf(v0[r] - mnew);
                p1[r] = __expf(v1[r] - mnew);
                rs += p0[r] + p1[r];
            }
            rs += __shfl_xor(rs, 16, 64);
            rs += __shfl_xor(rs, 32, 64);
            lrow = lrow * alpha + rs;
            mrow = mnew;
#pragma unroll
            for (int t = 0; t < 8; t++) oacc[t] *= alpha;

            u16x4 pk0, pk1;
#pragma unroll
            for (int r = 0; r < 4; r++) { pk0[r] = f2bf(p0[r]); pk1[r] = f2bf(p1[r]); }
            *(u16x4*)&pb[l16][quad * 4]      = pk0;   // P[q=l16][k=quad*4+r]
            *(u16x4*)&pb[l16][16 + quad * 4] = pk1;
            asm volatile("s_waitcnt lgkmcnt(0)" ::: "memory");
            bf16x8 pfrag = *(const bf16x8*)(&pb[l16][quad * 8]);

            // out^T: oacc[t] reg r = out[q=qrow][d = t*16 + quad*4 + r]
#pragma unroll
            for (int t = 0; t < 8; t++)
                oacc[t] = __builtin_amdgcn_mfma_f32_16x16x32_bf16(vfr[t], pfrag,
                                                                  oacc[t], 0, 0, 0);
        }
    }

    const float linv = 1.0f / lrow;
#pragma unroll
    for (int t = 0; t < 8; t++) {
        u16x4 ov;
#pragma unroll
        for (int r = 0; r < 4; r++) ov[r] = f2bf(oacc[t][r] * linv);
        *(u16x4*)&attn[(size_t)qrow * (NH * DV) + h * DV + t * 16 + quad * 4] = ov;
    }
}

// ---------------------------------------------------------------------------
extern "C" void kernel_launch(void* const* d_in, const int* in_sizes, int n_in,
                              void* d_out, int out_size, void* d_ws, size_t ws_size,
                              hipStream_t stream)
{
    const float* hid      = (const float*)d_in[0];
    // d_in[1] = position_ids (== arange(s)); sequence index used directly.
    const float* q_a_w    = (const float*)d_in[2];
    const float* q_a_ln_w = (const float*)d_in[3];
    const float* q_b_w    = (const float*)d_in[4];
    const float* kv_a_w   = (const float*)d_in[5];
    const float* kv_a_ln_w= (const float*)d_in[6];
    const float* kv_b_w   = (const float*)d_in[7];
    const float* o_w      = (const float*)d_in[8];

    const int NQKV = QR + KVR + DR;   // 2112: merged q_a_w ++ kv_a_w rows

    char* base = (char*)d_ws;
    u16* qkvaw_b = (u16*)(base + 0);          //  8,650,752  [2112,2048]
    u16* qbw_b   = (u16*)(base + 8650752);    //  9,437,184  [3072,1536]
    u16* kvbw_b  = (u16*)(base + 18087936);   //  4,194,304  [4096,512]
    u16* ow_b    = (u16*)(base + 22282240);   //  8,388,608  [2048,2048]
    u16* hid_b   = (u16*)(base + 30670848);   //  8,388,608  [2048,2048]
    u16* qkv_a   = (u16*)(base + 39059456);   //  8,650,752  [2048,2112]
    u16* q_n     = (u16*)(base + 47710208);   //  6,291,456  [2048,1536]
    u16* ckv     = (u16*)(base + 54001664);   //  2,097,152  [2048,512]
    u16* qb      = (u16*)(base + 56098816);   // 12,582,912  [2048,3072]
    u16* kvb     = (u16*)(base + 68681728);   // 16,777,216  [2048,4096]
    u16* Qb      = (u16*)(base + 85458944);   // 12,582,912  [16][2048][192]
    u16* Kb      = (u16*)(base + 98041856);   // 12,582,912
    u16* Vtb     = (u16*)(base + 110624768);  //  8,388,608  [16][128][2048]
    u16* attnb   = (u16*)(base + 39059456);   // reuse qkv_a (dead after rope)

    // 0) convert f32 inputs/weights to bf16
    cvt_f2b<<<HIDDEN_ * S_LEN / 1024, 256, 0, stream>>>(hid, hid_b, HIDDEN_ * S_LEN);
    cvt_f2b<<<QR * HIDDEN_ / 1024, 256, 0, stream>>>(q_a_w, qkvaw_b, QR * HIDDEN_);
    cvt_f2b<<<(KVR + DR) * HIDDEN_ / 1024, 256, 0, stream>>>(
        kv_a_w, qkvaw_b + (size_t)QR * HIDDEN_, (KVR + DR) * HIDDEN_);
    cvt_f2b<<<NH * DQK * QR / 1024, 256, 0, stream>>>(q_b_w, qbw_b, NH * DQK * QR);
    cvt_f2b<<<NH * 256 * KVR / 1024, 256, 0, stream>>>(kv_b_w, kvbw_b, NH * 256 * KVR);
    cvt_f2b<<<HIDDEN_ * NH * DV / 1024, 256, 0, stream>>>(o_w, ow_b, HIDDEN_ * NH * DV);

    // 1) qkv_a = hidden @ [q_a_w; kv_a_w]^T   [2048,2112]
    gemm_bt<<<dim3((NQKV + 127) / 128, S_LEN / 128), 256, 0, stream>>>(
        hid_b, qkvaw_b, qkv_a, S_LEN, NQKV, HIDDEN_, 0);
    // 2) q_n = rmsnorm(qkv_a[:, :1536])
    rmsnorm_k<<<S_LEN, 256, 0, stream>>>(qkv_a, q_a_ln_w, q_n, NQKV, QR, QR);
    // 3) ckv = rmsnorm(qkv_a[:, 1536:2048])
    rmsnorm_k<<<S_LEN, 256, 0, stream>>>(qkv_a + QR, kv_a_ln_w, ckv, NQKV, KVR, KVR);
    // 4) qb = q_n @ q_b_w^T           [2048,3072]
    gemm_bt<<<dim3(NH * DQK / 128, S_LEN / 128), 256, 0, stream>>>(
        q_n, qbw_b, qb, S_LEN, NH * DQK, QR, 0);
    // 5) kvb = ckv @ kv_b_w^T         [2048,4096]
    gemm_bt<<<dim3(NH * 256 / 128, S_LEN / 128), 256, 0, stream>>>(
        ckv, kvbw_b, kvb, S_LEN, NH * 256, KVR, 0);
    // 6) rope + repack Q/K (k_pe = qkv_a cols 2048..2111)
    rope_repack<<<S_LEN, 256, 0, stream>>>(qb, kvb, qkv_a + QR + KVR, NQKV, Qb, Kb);
    // 6b) V transpose: Vt[h][d][s]
    transpose_v<<<dim3(S_LEN / 64, DV / 64, NH), 256, 0, stream>>>(kvb, Vtb);
    // 7) causal flash attention -> attnb [2048, 2048]
    mla_attn<<<dim3(32, NH), 256, 0, stream>>>(Qb, Kb, Vtb, attnb);
    // 8) out = attnb @ o_w^T          [2048,2048], f32 output
    gemm_bt<<<dim3(HIDDEN_ / 128, S_LEN / 128), 256, 0, stream>>>(
        attnb, ow_b, (float*)d_out, S_LEN, HIDDEN_, HIDDEN_, 1);
}